// Round 1
// baseline (88.863 us; speedup 1.0000x reference)
//
#include <hip/hip_runtime.h>
#include <math.h>

#define TWO_N 512
#define DM    256
#define NT    256

// ws layout (bytes):
//   R     : [512*512] float  @ 0          (1 MB)
//   tsort : [512] float      @ 1048576
//   perm  : [512] int        @ 1050624
//   inv   : [512] int        @ 1052672
//   acc   : double           @ 1054720    (8-byte aligned)
//   cnt   : unsigned         @ 1054728
#define OFF_TSORT 1048576
#define OFF_PERM  1050624
#define OFF_INV   1052672
#define OFF_ACC   1054720
#define OFF_CNT   1054728

#define ACC4(acc, A, B) { float _d;                      \
    _d = (A).x - (B).x; acc += _d * _d;                  \
    _d = (A).y - (B).y; acc += _d * _d;                  \
    _d = (A).z - (B).z; acc += _d * _d;                  \
    _d = (A).w - (B).w; acc += _d * _d; }

// Blocks 0..255: 32x32 distance tiles (squared-diff "GEMM"), coalesced.
// Block 256: bitonic sort of targets -> tsort/perm/inv, plus zero-init of
//            the cross-block accumulator/counter used by supcr_rows.
__global__ __launch_bounds__(NT) void supcr_dist_sort(
    const float* __restrict__ E, const float* __restrict__ T,
    float* __restrict__ R, float* __restrict__ tsort,
    int* __restrict__ perm, int* __restrict__ inv,
    double* __restrict__ acc, unsigned* __restrict__ cnt)
{
    const int bid = blockIdx.x;
    const int t   = threadIdx.x;

    if (bid < 256) {
        // LDS rows padded to 65 float4 (260 floats): tx-strided reads land on
        // distinct-ish banks (2-way worst case = free).
        __shared__ float4 As4[32 * 65];
        __shared__ float4 Bs4[32 * 65];
        const int it = bid >> 4, jt = bid & 15;
        const float4* __restrict__ E4 = reinterpret_cast<const float4*>(E);

        for (int idx = t; idx < 32 * 64; idx += NT) {    // coalesced staging
            const int row = idx >> 6, c4 = idx & 63;
            As4[row * 65 + c4] = E4[(it * 32 + row) * 64 + c4];
            Bs4[row * 65 + c4] = E4[(jt * 32 + row) * 64 + c4];
        }
        __syncthreads();

        const int ty = t >> 4, tx = t & 15;
        float a00 = 0.f, a01 = 0.f, a10 = 0.f, a11 = 0.f;
        #pragma unroll 8
        for (int k4 = 0; k4 < 64; ++k4) {
            const float4 a0 = As4[ty * 65 + k4];
            const float4 a1 = As4[(ty + 16) * 65 + k4];
            const float4 b0 = Bs4[tx * 65 + k4];
            const float4 b1 = Bs4[(tx + 16) * 65 + k4];
            ACC4(a00, a0, b0); ACC4(a01, a0, b1);
            ACC4(a10, a1, b0); ACC4(a11, a1, b1);
        }
        const int r0 = it * 32 + ty, r1 = r0 + 16;
        const int c0 = jt * 32 + tx, c1 = c0 + 16;
        R[r0 * TWO_N + c0] = sqrtf(a00);
        R[r0 * TWO_N + c1] = sqrtf(a01);
        R[r1 * TWO_N + c0] = sqrtf(a10);
        R[r1 * TWO_N + c1] = sqrtf(a11);
    } else {
        // zero-init cross-block reduction state (visible to the next kernel
        // via the kernel-boundary release/acquire on the same stream)
        if (t == 0) { *acc = 0.0; *cnt = 0u; }

        // single-block bitonic sort of 512 (target, index) pairs
        __shared__ float key[TWO_N];
        __shared__ int   pay[TWO_N];
        key[t] = T[t]; key[t + 256] = T[t + 256];
        pay[t] = t;    pay[t + 256] = t + 256;
        __syncthreads();
        for (int kk = 2; kk <= TWO_N; kk <<= 1) {
            for (int j = kk >> 1; j > 0; j >>= 1) {
                #pragma unroll
                for (int w = 0; w < 2; ++w) {
                    const int e = t + w * 256;
                    const int p = e ^ j;
                    if (p > e) {
                        const float a = key[e], b = key[p];
                        const int  pa = pay[e], pb = pay[p];
                        const bool up = ((e & kk) == 0);
                        if (up ? (a > b) : (a < b)) {
                            key[e] = b; key[p] = a;
                            pay[e] = pb; pay[p] = pa;
                        }
                    }
                }
                __syncthreads();
            }
        }
        tsort[t] = key[t];           tsort[t + 256] = key[t + 256];
        perm[t]  = pay[t];           perm[t + 256]  = pay[t + 256];
        inv[pay[t]] = t;             inv[pay[t + 256]] = t + 256;
    }
}

// One block per row i: prefix-sum of s~ in t-sorted order, then per k the
// denom = S_tot - sum over the contiguous interval {d < theta}.
// Finalize fused in: each block atomicAdds its row sum into *acc (f64 HW
// atomic, device scope), and the last block to bump *cnt writes the output.
__global__ __launch_bounds__(NT) void supcr_rows(
    const float* __restrict__ T, const float* __restrict__ R,
    const float* __restrict__ tsort, const int* __restrict__ perm,
    const int* __restrict__ inv, double* __restrict__ acc,
    unsigned* __restrict__ cnt, float* __restrict__ out)
{
    const int i = blockIdx.x;
    const int t = threadIdx.x;

    __shared__ float  ts[TWO_N];
    __shared__ float  P[TWO_N];     // becomes inclusive prefix sums
    __shared__ double red[NT];

    const float ti = T[i];

    #pragma unroll
    for (int w = 0; w < 2; ++w) {
        const int m = t + w * 256;
        ts[m] = tsort[m];
        const int pj = perm[m];
        P[m] = (pj == i) ? 0.f : __expf(-R[(size_t)i * TWO_N + pj]);
    }
    __syncthreads();

    // inclusive prefix sum (Hillis-Steele), 2 elements/thread
    for (int off = 1; off < TWO_N; off <<= 1) {
        const float v0 = (t >= off)       ? P[t - off]       : 0.f;
        const float v1 = (t + 256 >= off) ? P[t + 256 - off] : 0.f;
        __syncthreads();
        P[t]       += v0;
        P[t + 256] += v1;
        __syncthreads();
    }

    const float Stot = P[TWO_N - 1];
    const int   mi   = inv[i];       // sorted position of t_i

    float local = 0.f;
    #pragma unroll
    for (int w = 0; w < 2; ++w) {
        const int k = t + w * 256;
        if (k == i) continue;
        const float theta = fabsf(ti - T[k]);
        const float rik   = R[(size_t)i * TWO_N + k];

        // left arm [0, mi]: d(m)=fabsf(ti-ts[m]) non-increasing.
        // count leading elements with d >= theta (monotone prefix).
        const int nl = mi + 1;
        int pos = 0;
        #pragma unroll
        for (int step = 512; step >= 1; step >>= 1) {
            const int np = pos + step;
            if (np <= nl && fabsf(ti - ts[np - 1]) >= theta) pos = np;
        }
        const int cl = nl - pos;                 // suffix with d < theta

        // right arm [mi, 511]: d non-decreasing. count leading d < theta.
        const int nr = TWO_N - mi;
        int pr = 0;
        #pragma unroll
        for (int step = 512; step >= 1; step >>= 1) {
            const int np = pr + step;
            if (np <= nr && fabsf(ti - ts[mi + np - 1]) < theta) pr = np;
        }
        const int cr = pr;

        // interval with d < theta: [mi-cl+1, mi+cr-1]
        float inner = 0.f;
        const int L  = mi - cl + 1;
        const int Rr = mi + cr - 1;
        if (Rr >= L) inner = P[Rr] - ((L > 0) ? P[L - 1] : 0.f);
        const float denom = Stot - inner;        // = sum over {d >= theta, j != i}
        local += -rik - logf(denom);
    }

    red[t] = (double)local;
    __syncthreads();
    for (int off = NT / 2; off > 0; off >>= 1) {
        if (t < off) red[t] += red[t + off];
        __syncthreads();
    }
    if (t == 0) {
        atomicAdd(acc, red[0]);          // device-scope f64 HW atomic
        __threadfence();                 // order acc-add before cnt-inc
        const unsigned old = atomicAdd(cnt, 1u);
        if (old == TWO_N - 1) {
            // all 512 adds fenced before their cnt bumps -> RMW sees total
            const double total = atomicAdd(acc, 0.0);
            out[0] = (float)(-total / (double)((long long)TWO_N * (TWO_N - 1)));
        }
    }
}

extern "C" void kernel_launch(void* const* d_in, const int* in_sizes, int n_in,
                              void* d_out, int out_size, void* d_ws, size_t ws_size,
                              hipStream_t stream) {
    (void)in_sizes; (void)n_in; (void)out_size; (void)ws_size;
    const float* E = (const float*)d_in[0];   // [512,256] fp32
    const float* T = (const float*)d_in[1];   // [512]     fp32
    float* out = (float*)d_out;

    char* ws = (char*)d_ws;
    float*    R      = (float*)(ws);
    float*    tsortp = (float*)(ws + OFF_TSORT);
    int*      permp  = (int*)(ws + OFF_PERM);
    int*      invp   = (int*)(ws + OFF_INV);
    double*   accp   = (double*)(ws + OFF_ACC);
    unsigned* cntp   = (unsigned*)(ws + OFF_CNT);

    supcr_dist_sort<<<257, NT, 0, stream>>>(E, T, R, tsortp, permp, invp, accp, cntp);
    supcr_rows<<<TWO_N, NT, 0, stream>>>(T, R, tsortp, permp, invp, accp, cntp, out);
}